// Round 7
// baseline (240.705 us; speedup 1.0000x reference)
//
#include <hip/hip_runtime.h>
#include <hip/hip_fp16.h>
#include <math.h>

#define NEG_SLOPE 0.2f

__device__ __forceinline__ float sigm(float x) { return 1.0f / (1.0f + __expf(-x)); }
__device__ __forceinline__ float tanh_fast(float x) {
    float xc = fminf(fmaxf(x, -15.0f), 15.0f);
    float e2 = __expf(2.0f * xc);
    return (e2 - 1.0f) / (e2 + 1.0f);
}
__device__ __forceinline__ float lrelu(float x) { return (x > 0.0f) ? x : NEG_SLOPE * x; }

typedef _Float16 h2v __attribute__((ext_vector_type(2)));
__device__ __forceinline__ float fdot2h(h2v a, h2v b, float c) {
#if __has_builtin(__builtin_amdgcn_fdot2)
    return __builtin_amdgcn_fdot2(a, b, c, false);
#else
    return (float)a[0] * (float)b[0] + (float)a[1] * (float)b[1] + c;
#endif
}

// ---------------- K0: zero deg ----------------
__global__ void k_zero(int* __restrict__ deg, int N) {
    int i = blockIdx.x * 256 + threadIdx.x;
    if (i < N) deg[i] = 0;
}

// ---------------- K1: histogram of dst ----------------
__global__ void k_hist(const int* __restrict__ dst, int* __restrict__ deg, int E) {
    int e = blockIdx.x * 256 + threadIdx.x;
    if (e < E) atomicAdd(deg + dst[e], 1);
}

// ---------------- scan (3 kernels, multi-block) ----------------
__global__ __launch_bounds__(256) void k_scan1(const int* __restrict__ deg,
                                               int* __restrict__ blksum, int N) {
    __shared__ int s[256];
    int tid = threadIdx.x;
    int i = blockIdx.x * 256 + tid;
    int v = (i < N) ? deg[i] : 0;
    s[tid] = v;
    __syncthreads();
    #pragma unroll
    for (int off = 128; off > 0; off >>= 1) {
        if (tid < off) s[tid] += s[tid + off];
        __syncthreads();
    }
    if (tid == 0) blksum[blockIdx.x] = s[0];
}

__global__ __launch_bounds__(256) void k_scan2(const int* __restrict__ blksum,
                                               int* __restrict__ blkoff, int nb) {
    __shared__ int s[256];
    int tid = threadIdx.x;
    int v = (tid < nb) ? blksum[tid] : 0;
    s[tid] = v;
    __syncthreads();
    for (int off = 1; off < 256; off <<= 1) {
        int t = (tid >= off) ? s[tid - off] : 0;
        __syncthreads();
        s[tid] += t;
        __syncthreads();
    }
    if (tid < nb) blkoff[tid] = s[tid] - v;   // exclusive
}

__global__ __launch_bounds__(256) void k_scan3(const int* __restrict__ deg,
                                               const int* __restrict__ blkoff,
                                               int* __restrict__ rowptr,
                                               int* __restrict__ cursor, int N, int E) {
    __shared__ int s[256];
    int tid = threadIdx.x;
    int i = blockIdx.x * 256 + tid;
    int v = (i < N) ? deg[i] : 0;
    s[tid] = v;
    __syncthreads();
    for (int off = 1; off < 256; off <<= 1) {
        int t = (tid >= off) ? s[tid - off] : 0;
        __syncthreads();
        s[tid] += t;
        __syncthreads();
    }
    int excl = s[tid] - v + blkoff[blockIdx.x];
    if (i < N) { rowptr[i] = excl; cursor[i] = excl; }
    if (i == N - 1) rowptr[N] = E;
}

// ---------------- K3: scatter edges into CSR (by dst) ----------------
__global__ void k_scatter(const int* __restrict__ src, const int* __restrict__ dst,
                          int* __restrict__ cursor, int* __restrict__ csr_src, int E) {
    int e = blockIdx.x * 256 + threadIdx.x;
    if (e < E) {
        int pos = atomicAdd(cursor + dst[e], 1);
        csr_src[pos] = src[e];
    }
}

// ---------------- K4a: wa_src[k][h] ----------------
__global__ void k_pre(const float* __restrict__ W_gat, const float* __restrict__ a_src,
                      const float* __restrict__ a_dst, float* __restrict__ wa) {
    int tid = threadIdx.x;          // tid = k*8 + h
    int k = tid >> 3, h = tid & 7;
    float s1 = 0.0f, s2 = 0.0f;
    for (int c = 0; c < 32; ++c) {
        float wv = W_gat[k * 256 + h * 32 + c];
        s1 += wv * a_src[h * 32 + c];
        s2 += wv * a_dst[h * 32 + c];
    }
    wa[tid] = s1;
    wa[256 + tid] = s2;
}

// ---------------- K4b: asrc/adst = x @ wa ----------------
__global__ __launch_bounds__(256) void k_att(const float* __restrict__ x,
                                             const float* __restrict__ wa,
                                             float* __restrict__ asrc,
                                             float* __restrict__ adst) {
    __shared__ float xs[32 * 33];
    __shared__ float was[256], wad[256];
    int tid = threadIdx.x;
    int n0 = blockIdx.x * 32;
    for (int i = tid; i < 1024; i += 256) {
        int nl = i >> 5, k = i & 31;
        xs[nl * 33 + k] = x[(size_t)(n0 + nl) * 32 + k];
    }
    was[tid] = wa[tid];
    wad[tid] = wa[256 + tid];
    __syncthreads();
    int nl = tid >> 3, h = tid & 7;
    float s1 = 0.0f, s2 = 0.0f;
    #pragma unroll
    for (int k = 0; k < 32; ++k) {
        float xv = xs[nl * 33 + k];
        s1 += xv * was[k * 8 + h];
        s2 += xv * wad[k * 8 + h];
    }
    asrc[(size_t)(n0 + nl) * 8 + h] = s1;
    adst[(size_t)(n0 + nl) * 8 + h] = s2;
}

// ---------------- K5: GAT gather ----------------
__global__ __launch_bounds__(256) void k_gat(
    const int* __restrict__ rowptr, const int* __restrict__ csr_src,
    const float* __restrict__ asrc, const float* __restrict__ adst,
    const float* __restrict__ x, float* __restrict__ z, int N) {
    int w = (blockIdx.x * 256 + threadIdx.x) >> 6;
    int lane = threadIdx.x & 63;
    if (w >= N) return;
    int r0 = rowptr[w], r1 = rowptr[w + 1];
    int h = lane >> 3, kq = lane & 7;
    float ad = adst[w * 8 + h];
    float4 acc = make_float4(0.0f, 0.0f, 0.0f, 0.0f);
    float den = 0.0f;
    const float4* x4 = (const float4*)x;
    for (int i = r0; i < r1; ++i) {
        int s = csr_src[i];
        float ew = __expf(lrelu(asrc[s * 8 + h] + ad));
        float4 xv = x4[(size_t)s * 8 + kq];
        acc.x += ew * xv.x; acc.y += ew * xv.y;
        acc.z += ew * xv.z; acc.w += ew * xv.w;
        den += ew;
    }
    float inv = 1.0f / fmaxf(den, 1e-16f);
    float4 r = make_float4(acc.x * inv, acc.y * inv, acc.z * inv, acc.w * inv);
    ((float4*)z)[(size_t)w * 64 + lane] = r;
}

// ---------------- K5b: gatT[b][c][node] = z[node,:] @ M[:,c] + b_gat[c] ----------------
__global__ __launch_bounds__(256) void k_zw(
    const float* __restrict__ z, const float* __restrict__ W_gat,
    const float* __restrict__ b_gat, float* __restrict__ gatT, int N, int n_node) {
    int gw = (blockIdx.x * 256 + threadIdx.x) >> 6;  // 0..7999
    int lane = threadIdx.x & 63;
    int chalf = gw & 1;
    int nset = gw >> 1;                               // 0..3999
    int c = chalf * 16 + (lane & 15);
    int sl = lane >> 4;
    float wcol[64];
    #pragma unroll
    for (int i = 0; i < 64; ++i) {
        int k = i & 31, hh = sl * 2 + (i >> 5);
        wcol[i] = 0.125f * W_gat[k * 256 + hh * 32 + c];
    }
    float bg = b_gat[c];
    const float4* z4 = (const float4*)z;
    for (int it = 0; it < 8; ++it) {
        int n = nset * 8 + it;
        if (n >= N) break;
        float p = 0.0f;
        #pragma unroll
        for (int k4 = 0; k4 < 16; ++k4) {
            float4 zv = z4[(size_t)n * 64 + sl * 16 + k4];
            p += zv.x * wcol[4 * k4] + zv.y * wcol[4 * k4 + 1]
               + zv.z * wcol[4 * k4 + 2] + zv.w * wcol[4 * k4 + 3];
        }
        p += __shfl_xor(p, 16, 64);
        p += __shfl_xor(p, 32, 64);
        if (lane < 16) {
            int b = n / n_node, kk = n - b * n_node;
            gatT[((size_t)b * 32 + c) * n_node + kk] = p + bg;
        }
    }
}

// ---------------- K6a: transpose W_ih1 [128][n_node] -> Wt [n_node][128] ----------------
__global__ __launch_bounds__(256) void k_wt(const float* __restrict__ W,
                                            float* __restrict__ Wt, int n_node) {
    __shared__ float tle[32][33];
    int kt = blockIdx.x & 31;
    int gt = blockIdx.x >> 5;
    int tid = threadIdx.x;
    for (int i = tid; i < 1024; i += 256) {
        int gl = i >> 5, kl = i & 31;
        int g = gt * 32 + gl, k = kt * 32 + kl;
        tle[gl][kl] = (k < n_node) ? W[(size_t)g * n_node + k] : 0.0f;
    }
    __syncthreads();
    for (int i = tid; i < 1024; i += 256) {
        int kl = i >> 5, gl = i & 31;
        int k = kt * 32 + kl, g = gt * 32 + gl;
        if (k < n_node) Wt[(size_t)k * 128 + g] = tle[gl][kl];
    }
}

// ---------------- K6c: pack LSTM weights, eighth-split layout ----------------
// k_lstm thread t (0..1023): n = t>>3 (unit), q = t&7 (k-slice).
// wc2[j*1024+t] (uint4, fp16x8), j in [0,8): g=j>>1, jj=j&1:
//     W_hh2[(g*128+n)*128 + q*16 + jj*8 .. +8)
// wif4[j*1024+t] (float4), j in [0,4): W_ih2[(j*128+n)*32 + q*4 .. +4)
// w1f4[j*128+t1] (float4), t1 in [0,128), r1=(t1&3)*32+(t1>>2), j in [0,8):
//     W_hh1[r1*32 + j*4 .. +4)
__global__ __launch_bounds__(256) void k_pack2(
    const float* __restrict__ W_hh2, const float* __restrict__ W_ih2,
    const float* __restrict__ W_hh1,
    uint4* __restrict__ wc2, float4* __restrict__ wif4, float4* __restrict__ w1f4) {
    int i = blockIdx.x * 256 + threadIdx.x;
    if (i < 8192) {
        int j = i >> 10, t = i & 1023;
        int n = t >> 3, q = t & 7;
        int g = j >> 1, jj = j & 1;
        const float* p = W_hh2 + (size_t)(g * 128 + n) * 128 + q * 16 + jj * 8;
        __align__(16) _Float16 tmp[8];
        #pragma unroll
        for (int k = 0; k < 8; ++k) tmp[k] = (_Float16)p[k];
        wc2[j * 1024 + t] = *(const uint4*)tmp;
    } else if (i < 12288) {
        int ii = i - 8192;
        int j = ii >> 10, t = ii & 1023;
        int n = t >> 3, q = t & 7;
        wif4[j * 1024 + t] = *(const float4*)(W_ih2 + (size_t)(j * 128 + n) * 32 + q * 4);
    } else if (i < 13312) {
        int ii = i - 12288;
        int j = ii >> 7, t1 = ii & 127;
        int r1 = (t1 & 3) * 32 + (t1 >> 2);
        w1f4[j * 128 + t1] = *(const float4*)(W_hh1 + (size_t)r1 * 32 + j * 4);
    }
}

// ---------------- K6b: P1[t,b,g] = bias + dot(Wt[:, g], gatT[b][t][:]) ----------------
__global__ __launch_bounds__(256) void k_p1(
    const float* __restrict__ gatT, const float* __restrict__ Wt,
    const float* __restrict__ b_ih1, const float* __restrict__ b_hh1,
    float* __restrict__ P1, int n_node, int B) {
    __shared__ __align__(16) float Arow[2][1024];
    __shared__ __align__(16) float part[4][2][128];
    int blk = blockIdx.x;
    int b = blk >> 4;
    int tq = blk & 15;
    int tid = threadIdx.x;
    const float* A0 = gatT + ((size_t)b * 32 + tq * 2) * n_node;
    #pragma unroll
    for (int r = 0; r < 2; ++r)
        for (int i = tid; i < n_node; i += 256)
            Arow[r][i] = A0[(size_t)r * n_node + i];
    __syncthreads();

    int g4 = tid & 31;
    int tloc = (tid >> 5) & 1;
    int ks = tid >> 6;
    int kq = n_node >> 2;            // 250
    int k0 = ks * kq;
    const float4* Wt4 = (const float4*)Wt;
    float4 acc = make_float4(0.0f, 0.0f, 0.0f, 0.0f);
    #pragma unroll 4
    for (int k = 0; k < kq; ++k) {
        float4 w = Wt4[(size_t)(k0 + k) * 32 + g4];
        float a = Arow[tloc][k0 + k];
        acc.x += w.x * a; acc.y += w.y * a;
        acc.z += w.z * a; acc.w += w.w * a;
    }
    *(float4*)&part[ks][tloc][g4 * 4] = acc;
    __syncthreads();

    int tl = tid >> 7, g = tid & 127;
    float s = part[0][tl][g] + part[1][tl][g] + part[2][tl][g] + part[3][tl][g]
            + b_ih1[g] + b_hh1[g];
    int t = tq * 2 + tl;
    P1[((size_t)t * B + b) * 128 + g] = s;
}

// ---------------- K7: pipelined LSTM1 || LSTM2, eighth-split, f32 L1/input-proj ----------------
// 1024 threads = 16 waves (4 waves/SIMD). Thread (n=tid>>3, q=tid&7) owns all 4
// gate rows of unit n over a k-slice: 16 dims of h2 (fp16, wc 8xuint4 = 32 VGPR)
// + 4 dims of h1 (f32, wi 4xfloat4 = 16 VGPR). Per step 3 LDS reads, 8-lane
// butterfly shfl_xor(1,2,4) per gate. LSTM1 on threads<128, all-f32 (R5 numerics).
// PARITY FIX vs R6: LSTM2 reads h1 from h1d[s&1] (h1[s-1], written at superstep
// s-1 into h1d[((s-1)+1)&1]); R6 read h1d[(s-1)&1] = stale h1[s-2] / race.
__attribute__((amdgpu_waves_per_eu(4, 4)))
__global__ __launch_bounds__(1024) void k_lstm(
    const float* __restrict__ P1, const uint4* __restrict__ wc2,
    const float4* __restrict__ wif4, const float4* __restrict__ w1f4,
    const float* __restrict__ b_ih2, const float* __restrict__ b_hh2,
    float* __restrict__ h2finT, int B, int T) {
    __shared__ __align__(16) float P1s[32][128];     // 16KB
    __shared__ __align__(16) float h1d[2][32];       // f32 LSTM1 state, dbuf
    __shared__ __align__(16) __half hbuf[2][128];    // fp16 LSTM2 state, dbuf
    int tid = threadIdx.x, b = blockIdx.x;
    int n = tid >> 3, q = tid & 7;

    for (int i = tid; i < 4096; i += 1024)
        P1s[i >> 7][i & 127] = P1[((size_t)(i >> 7) * B + b) * 128 + (i & 127)];

    uint4 wc[8];
    #pragma unroll
    for (int j = 0; j < 8; ++j) wc[j] = wc2[j * 1024 + tid];
    float4 wi0 = wif4[tid];
    float4 wi1 = wif4[1024 + tid];
    float4 wi2 = wif4[2048 + tid];
    float4 wi3 = wif4[3072 + tid];
    float bias0 = b_ih2[n] + b_hh2[n];
    float bias1 = b_ih2[128 + n] + b_hh2[128 + n];
    float bias2 = b_ih2[256 + n] + b_hh2[256 + n];
    float bias3 = b_ih2[384 + n] + b_hh2[384 + n];

    int gt1 = tid & 3;
    int r1 = gt1 * 32 + (tid >> 2);   // valid for tid<128
    float4 w1[8];
    if (tid < 128) {
        #pragma unroll
        for (int j = 0; j < 8; ++j) w1[j] = w1f4[j * 128 + tid];
    }
    if (tid < 32) h1d[0][tid] = 0.0f;
    if (tid < 128) hbuf[0][tid] = __float2half(0.0f);
    float c1 = 0.0f, c2 = 0.0f;
    __syncthreads();

    for (int s = 0; s <= T; ++s) {
        // ---- LSTM2 step t2 = s-1 (all threads) ----
        if (s >= 1) {
            int t2 = s - 1;
            const uint4* hb = (const uint4*)hbuf[t2 & 1];
            uint4 h2a = hb[q * 2];
            uint4 h2b = hb[q * 2 + 1];
            float4 h1v = ((const float4*)h1d[s & 1])[q];   // h1[s-1]  (PARITY FIX)
            const h2v* ha = reinterpret_cast<const h2v*>(&h2a);
            const h2v* hc = reinterpret_cast<const h2v*>(&h2b);
            // input projection (f32)
            float sg0 = wi0.x * h1v.x + wi0.y * h1v.y + wi0.z * h1v.z + wi0.w * h1v.w;
            float sg1 = wi1.x * h1v.x + wi1.y * h1v.y + wi1.z * h1v.z + wi1.w * h1v.w;
            float sg2 = wi2.x * h1v.x + wi2.y * h1v.y + wi2.z * h1v.z + wi2.w * h1v.w;
            float sg3 = wi3.x * h1v.x + wi3.y * h1v.y + wi3.z * h1v.z + wi3.w * h1v.w;
            // recurrent 16-dim fp16 slices, 4 gates
            {
                const h2v* wa_ = reinterpret_cast<const h2v*>(&wc[0]);
                const h2v* wb_ = reinterpret_cast<const h2v*>(&wc[1]);
                float a0 = 0, a1 = 0, a2 = 0, a3 = 0;
                a0 = fdot2h(wa_[0], ha[0], a0); a1 = fdot2h(wa_[1], ha[1], a1);
                a2 = fdot2h(wa_[2], ha[2], a2); a3 = fdot2h(wa_[3], ha[3], a3);
                a0 = fdot2h(wb_[0], hc[0], a0); a1 = fdot2h(wb_[1], hc[1], a1);
                a2 = fdot2h(wb_[2], hc[2], a2); a3 = fdot2h(wb_[3], hc[3], a3);
                sg0 += (a0 + a1) + (a2 + a3);
            }
            {
                const h2v* wa_ = reinterpret_cast<const h2v*>(&wc[2]);
                const h2v* wb_ = reinterpret_cast<const h2v*>(&wc[3]);
                float a0 = 0, a1 = 0, a2 = 0, a3 = 0;
                a0 = fdot2h(wa_[0], ha[0], a0); a1 = fdot2h(wa_[1], ha[1], a1);
                a2 = fdot2h(wa_[2], ha[2], a2); a3 = fdot2h(wa_[3], ha[3], a3);
                a0 = fdot2h(wb_[0], hc[0], a0); a1 = fdot2h(wb_[1], hc[1], a1);
                a2 = fdot2h(wb_[2], hc[2], a2); a3 = fdot2h(wb_[3], hc[3], a3);
                sg1 += (a0 + a1) + (a2 + a3);
            }
            {
                const h2v* wa_ = reinterpret_cast<const h2v*>(&wc[4]);
                const h2v* wb_ = reinterpret_cast<const h2v*>(&wc[5]);
                float a0 = 0, a1 = 0, a2 = 0, a3 = 0;
                a0 = fdot2h(wa_[0], ha[0], a0); a1 = fdot2h(wa_[1], ha[1], a1);
                a2 = fdot2h(wa_[2], ha[2], a2); a3 = fdot2h(wa_[3], ha[3], a3);
                a0 = fdot2h(wb_[0], hc[0], a0); a1 = fdot2h(wb_[1], hc[1], a1);
                a2 = fdot2h(wb_[2], hc[2], a2); a3 = fdot2h(wb_[3], hc[3], a3);
                sg2 += (a0 + a1) + (a2 + a3);
            }
            {
                const h2v* wa_ = reinterpret_cast<const h2v*>(&wc[6]);
                const h2v* wb_ = reinterpret_cast<const h2v*>(&wc[7]);
                float a0 = 0, a1 = 0, a2 = 0, a3 = 0;
                a0 = fdot2h(wa_[0], ha[0], a0); a1 = fdot2h(wa_[1], ha[1], a1);
                a2 = fdot2h(wa_[2], ha[2], a2); a3 = fdot2h(wa_[3], ha[3], a3);
                a0 = fdot2h(wb_[0], hc[0], a0); a1 = fdot2h(wb_[1], hc[1], a1);
                a2 = fdot2h(wb_[2], hc[2], a2); a3 = fdot2h(wb_[3], hc[3], a3);
                sg3 += (a0 + a1) + (a2 + a3);
            }
            sg0 += __shfl_xor(sg0, 1, 64); sg0 += __shfl_xor(sg0, 2, 64); sg0 += __shfl_xor(sg0, 4, 64);
            sg1 += __shfl_xor(sg1, 1, 64); sg1 += __shfl_xor(sg1, 2, 64); sg1 += __shfl_xor(sg1, 4, 64);
            sg2 += __shfl_xor(sg2, 1, 64); sg2 += __shfl_xor(sg2, 2, 64); sg2 += __shfl_xor(sg2, 4, 64);
            sg3 += __shfl_xor(sg3, 1, 64); sg3 += __shfl_xor(sg3, 2, 64); sg3 += __shfl_xor(sg3, 4, 64);
            if (q == 0) {
                float i_ = sigm(sg0 + bias0), f_ = sigm(sg1 + bias1);
                float g_ = tanh_fast(sg2 + bias2), o_ = sigm(sg3 + bias3);
                c2 = f_ * c2 + i_ * g_;
                float h = o_ * tanh_fast(c2);
                hbuf[(t2 + 1) & 1][n] = __float2half(h);
                if (t2 == T - 1) h2finT[n * 32 + b] = h;
            }
        }
        // ---- LSTM1 step s (threads < 128, all-f32) ----
        if (tid < 128 && s < T) {
            const float4* hp = (const float4*)h1d[s & 1];
            float acc = P1s[s][r1];
            #pragma unroll
            for (int j = 0; j < 8; ++j) {
                float4 h = hp[j], w = w1[j];
                acc += w.x * h.x + w.y * h.y + w.z * h.z + w.w * h.w;
            }
            float v1 = __shfl_xor(acc, 1, 64);
            float v2 = __shfl_xor(acc, 2, 64);
            float v3 = __shfl_xor(acc, 3, 64);
            if (gt1 == 0) {
                float i_ = sigm(acc), f_ = sigm(v1);
                float g_ = tanh_fast(v2), o_ = sigm(v3);
                c1 = f_ * c1 + i_ * g_;
                float h = o_ * tanh_fast(c1);
                h1d[(s + 1) & 1][tid >> 2] = h;
            }
        }
        __syncthreads();
    }
}

// ---------------- K8: final linear from h2finT ----------------
__global__ __launch_bounds__(256) void k_fin(
    const float* __restrict__ h2finT, const float* __restrict__ W_lin,
    const float* __restrict__ b_lin, float* __restrict__ out, int n_node, int B) {
    __shared__ __align__(16) float hs[128];
    int b = blockIdx.x >> 3;
    int kc = blockIdx.x & 7;
    int tid = threadIdx.x;
    if (tid < 128) hs[tid] = h2finT[tid * 32 + b];
    __syncthreads();
    int outdim = n_node * 2;
    int kk = kc * 256 + tid;
    if (kk < outdim) {
        float acc = b_lin[kk];
        const float4* W4 = (const float4*)(W_lin + (size_t)kk * 128);
        const float4* h4 = (const float4*)hs;
        #pragma unroll 8
        for (int j = 0; j < 32; ++j) {
            float4 w = W4[j], h = h4[j];
            acc += w.x * h.x + w.y * h.y + w.z * h.z + w.w * h.w;
        }
        out[(size_t)b * outdim + kk] = acc;
    }
}

extern "C" void kernel_launch(void* const* d_in, const int* in_sizes, int n_in,
                              void* d_out, int out_size, void* d_ws, size_t ws_size,
                              hipStream_t stream) {
    const float* x     = (const float*)d_in[0];
    const int*   src   = (const int*)d_in[1];
    const int*   dst   = (const int*)d_in[2];
    const float* W_gat = (const float*)d_in[4];
    const float* a_src = (const float*)d_in[5];
    const float* a_dst = (const float*)d_in[6];
    const float* b_gat = (const float*)d_in[7];
    const float* W_ih1 = (const float*)d_in[8];
    const float* W_hh1 = (const float*)d_in[9];
    const float* b_ih1 = (const float*)d_in[10];
    const float* b_hh1 = (const float*)d_in[11];
    const float* W_ih2 = (const float*)d_in[12];
    const float* W_hh2 = (const float*)d_in[13];
    const float* b_ih2 = (const float*)d_in[14];
    const float* b_hh2 = (const float*)d_in[15];
    const float* W_lin = (const float*)d_in[16];
    const float* b_lin = (const float*)d_in[17];

    int N = in_sizes[0] / 32;          // 32000
    int E = in_sizes[1];               // 384000
    int n_node = in_sizes[8] / 128;    // 1000
    int B = N / n_node;                // 32
    int T = 32;

    float* ws = (float*)d_ws;
    float* z      = ws;                                 // N*256
    float* asrc   = z + (size_t)N * 256;                // N*8
    float* adst   = asrc + (size_t)N * 8;               // N*8
    float* gatT   = adst + (size_t)N * 8;               // N*32
    float* P1     = gatT + (size_t)N * 32;              // T*B*128
    float* wc2f   = P1 + (size_t)T * B * 128;           // 8192 uint4 = 32768 f32
    float* wiff   = wc2f + 32768;                       // 4096 float4 = 16384 f32
    float* w1ff   = wiff + 16384;                       // 1024 float4 = 4096 f32
    float* h2finT = w1ff + 4096;                        // 128*32
    float* wa     = h2finT + 128 * 32;                  // 512
    int* deg     = (int*)(wa + 512);                    // N
    int* cursor  = deg + N;                             // N
    int* rowptr  = cursor + N;                          // N+1
    int* csr_src = rowptr + N + 1;                      // E
    int* blksum  = csr_src + E;                         // 256
    int* blkoff  = blksum + 256;                        // 256
    float* Wt    = (float*)(((uintptr_t)(blkoff + 256) + 255) & ~(uintptr_t)255); // n_node*128

    uint4*  wc2  = (uint4*)wc2f;
    float4* wif4 = (float4*)wiff;
    float4* w1f4 = (float4*)w1ff;

    int nb = (N + 255) / 256;   // 125

    k_pack2<<<52, 256, 0, stream>>>(W_hh2, W_ih2, W_hh1, wc2, wif4, w1f4);
    k_wt<<<128, 256, 0, stream>>>(W_ih1, Wt, n_node);
    k_zero<<<(N + 255) / 256, 256, 0, stream>>>(deg, N);
    k_hist<<<(E + 255) / 256, 256, 0, stream>>>(dst, deg, E);
    k_scan1<<<nb, 256, 0, stream>>>(deg, blksum, N);
    k_scan2<<<1, 256, 0, stream>>>(blksum, blkoff, nb);
    k_scan3<<<nb, 256, 0, stream>>>(deg, blkoff, rowptr, cursor, N, E);
    k_scatter<<<(E + 255) / 256, 256, 0, stream>>>(src, dst, cursor, csr_src, E);
    k_pre<<<1, 256, 0, stream>>>(W_gat, a_src, a_dst, wa);
    k_att<<<N / 32, 256, 0, stream>>>(x, wa, asrc, adst);
    k_gat<<<(N * 64 + 255) / 256, 256, 0, stream>>>(rowptr, csr_src, asrc, adst,
                                                    x, z, N);
    k_zw<<<2000, 256, 0, stream>>>(z, W_gat, b_gat, gatT, N, n_node);
    k_p1<<<B * 16, 256, 0, stream>>>(gatT, Wt, b_ih1, b_hh1, P1, n_node, B);
    k_lstm<<<B, 1024, 0, stream>>>(P1, wc2, wif4, w1f4, b_ih2, b_hh2, h2finT, B, T);
    k_fin<<<B * 8, 256, 0, stream>>>(h2finT, W_lin, b_lin, (float*)d_out, n_node, B);
}

// Round 8
// 220.643 us; speedup vs baseline: 1.0909x; 1.0909x over previous
//
#include <hip/hip_runtime.h>
#include <hip/hip_fp16.h>
#include <math.h>

#define NEG_SLOPE 0.2f

__device__ __forceinline__ float sigm(float x) { return 1.0f / (1.0f + __expf(-x)); }
__device__ __forceinline__ float tanh_fast(float x) {
    float xc = fminf(fmaxf(x, -15.0f), 15.0f);
    float e2 = __expf(2.0f * xc);
    return (e2 - 1.0f) / (e2 + 1.0f);
}
__device__ __forceinline__ float lrelu(float x) { return (x > 0.0f) ? x : NEG_SLOPE * x; }

typedef _Float16 h2v __attribute__((ext_vector_type(2)));
__device__ __forceinline__ float fdot2h(h2v a, h2v b, float c) {
#if __has_builtin(__builtin_amdgcn_fdot2)
    return __builtin_amdgcn_fdot2(a, b, c, false);
#else
    return (float)a[0] * (float)b[0] + (float)a[1] * (float)b[1] + c;
#endif
}

// dot over 8 fp16 dims held as uint4 (4 x v_dot2)
__device__ __forceinline__ float dot16(const uint4& w, const uint4& h, float acc) {
    const h2v* wp = reinterpret_cast<const h2v*>(&w);
    const h2v* hp = reinterpret_cast<const h2v*>(&h);
    acc = fdot2h(wp[0], hp[0], acc);
    acc = fdot2h(wp[1], hp[1], acc);
    acc = fdot2h(wp[2], hp[2], acc);
    acc = fdot2h(wp[3], hp[3], acc);
    return acc;
}

// ---------------- K0: zero deg ----------------
__global__ void k_zero(int* __restrict__ deg, int N) {
    int i = blockIdx.x * 256 + threadIdx.x;
    if (i < N) deg[i] = 0;
}

// ---------------- K1: histogram of dst ----------------
__global__ void k_hist(const int* __restrict__ dst, int* __restrict__ deg, int E) {
    int e = blockIdx.x * 256 + threadIdx.x;
    if (e < E) atomicAdd(deg + dst[e], 1);
}

// ---------------- scan (3 kernels, multi-block) ----------------
__global__ __launch_bounds__(256) void k_scan1(const int* __restrict__ deg,
                                               int* __restrict__ blksum, int N) {
    __shared__ int s[256];
    int tid = threadIdx.x;
    int i = blockIdx.x * 256 + tid;
    int v = (i < N) ? deg[i] : 0;
    s[tid] = v;
    __syncthreads();
    #pragma unroll
    for (int off = 128; off > 0; off >>= 1) {
        if (tid < off) s[tid] += s[tid + off];
        __syncthreads();
    }
    if (tid == 0) blksum[blockIdx.x] = s[0];
}

__global__ __launch_bounds__(256) void k_scan2(const int* __restrict__ blksum,
                                               int* __restrict__ blkoff, int nb) {
    __shared__ int s[256];
    int tid = threadIdx.x;
    int v = (tid < nb) ? blksum[tid] : 0;
    s[tid] = v;
    __syncthreads();
    for (int off = 1; off < 256; off <<= 1) {
        int t = (tid >= off) ? s[tid - off] : 0;
        __syncthreads();
        s[tid] += t;
        __syncthreads();
    }
    if (tid < nb) blkoff[tid] = s[tid] - v;   // exclusive
}

__global__ __launch_bounds__(256) void k_scan3(const int* __restrict__ deg,
                                               const int* __restrict__ blkoff,
                                               int* __restrict__ rowptr,
                                               int* __restrict__ cursor, int N, int E) {
    __shared__ int s[256];
    int tid = threadIdx.x;
    int i = blockIdx.x * 256 + tid;
    int v = (i < N) ? deg[i] : 0;
    s[tid] = v;
    __syncthreads();
    for (int off = 1; off < 256; off <<= 1) {
        int t = (tid >= off) ? s[tid - off] : 0;
        __syncthreads();
        s[tid] += t;
        __syncthreads();
    }
    int excl = s[tid] - v + blkoff[blockIdx.x];
    if (i < N) { rowptr[i] = excl; cursor[i] = excl; }
    if (i == N - 1) rowptr[N] = E;
}

// ---------------- K3: scatter edges into CSR (by dst) ----------------
__global__ void k_scatter(const int* __restrict__ src, const int* __restrict__ dst,
                          int* __restrict__ cursor, int* __restrict__ csr_src, int E) {
    int e = blockIdx.x * 256 + threadIdx.x;
    if (e < E) {
        int pos = atomicAdd(cursor + dst[e], 1);
        csr_src[pos] = src[e];
    }
}

// ---------------- K4a: wa_src[k][h] ----------------
__global__ void k_pre(const float* __restrict__ W_gat, const float* __restrict__ a_src,
                      const float* __restrict__ a_dst, float* __restrict__ wa) {
    int tid = threadIdx.x;          // tid = k*8 + h
    int k = tid >> 3, h = tid & 7;
    float s1 = 0.0f, s2 = 0.0f;
    for (int c = 0; c < 32; ++c) {
        float wv = W_gat[k * 256 + h * 32 + c];
        s1 += wv * a_src[h * 32 + c];
        s2 += wv * a_dst[h * 32 + c];
    }
    wa[tid] = s1;
    wa[256 + tid] = s2;
}

// ---------------- K4b: asrc/adst = x @ wa ----------------
__global__ __launch_bounds__(256) void k_att(const float* __restrict__ x,
                                             const float* __restrict__ wa,
                                             float* __restrict__ asrc,
                                             float* __restrict__ adst) {
    __shared__ float xs[32 * 33];
    __shared__ float was[256], wad[256];
    int tid = threadIdx.x;
    int n0 = blockIdx.x * 32;
    for (int i = tid; i < 1024; i += 256) {
        int nl = i >> 5, k = i & 31;
        xs[nl * 33 + k] = x[(size_t)(n0 + nl) * 32 + k];
    }
    was[tid] = wa[tid];
    wad[tid] = wa[256 + tid];
    __syncthreads();
    int nl = tid >> 3, h = tid & 7;
    float s1 = 0.0f, s2 = 0.0f;
    #pragma unroll
    for (int k = 0; k < 32; ++k) {
        float xv = xs[nl * 33 + k];
        s1 += xv * was[k * 8 + h];
        s2 += xv * wad[k * 8 + h];
    }
    asrc[(size_t)(n0 + nl) * 8 + h] = s1;
    adst[(size_t)(n0 + nl) * 8 + h] = s2;
}

// ---------------- K5: GAT gather ----------------
__global__ __launch_bounds__(256) void k_gat(
    const int* __restrict__ rowptr, const int* __restrict__ csr_src,
    const float* __restrict__ asrc, const float* __restrict__ adst,
    const float* __restrict__ x, float* __restrict__ z, int N) {
    int w = (blockIdx.x * 256 + threadIdx.x) >> 6;
    int lane = threadIdx.x & 63;
    if (w >= N) return;
    int r0 = rowptr[w], r1 = rowptr[w + 1];
    int h = lane >> 3, kq = lane & 7;
    float ad = adst[w * 8 + h];
    float4 acc = make_float4(0.0f, 0.0f, 0.0f, 0.0f);
    float den = 0.0f;
    const float4* x4 = (const float4*)x;
    for (int i = r0; i < r1; ++i) {
        int s = csr_src[i];
        float ew = __expf(lrelu(asrc[s * 8 + h] + ad));
        float4 xv = x4[(size_t)s * 8 + kq];
        acc.x += ew * xv.x; acc.y += ew * xv.y;
        acc.z += ew * xv.z; acc.w += ew * xv.w;
        den += ew;
    }
    float inv = 1.0f / fmaxf(den, 1e-16f);
    float4 r = make_float4(acc.x * inv, acc.y * inv, acc.z * inv, acc.w * inv);
    ((float4*)z)[(size_t)w * 64 + lane] = r;
}

// ---------------- K5b: gatT[b][c][node] = z[node,:] @ M[:,c] + b_gat[c] ----------------
__global__ __launch_bounds__(256) void k_zw(
    const float* __restrict__ z, const float* __restrict__ W_gat,
    const float* __restrict__ b_gat, float* __restrict__ gatT, int N, int n_node) {
    int gw = (blockIdx.x * 256 + threadIdx.x) >> 6;  // 0..7999
    int lane = threadIdx.x & 63;
    int chalf = gw & 1;
    int nset = gw >> 1;                               // 0..3999
    int c = chalf * 16 + (lane & 15);
    int sl = lane >> 4;
    float wcol[64];
    #pragma unroll
    for (int i = 0; i < 64; ++i) {
        int k = i & 31, hh = sl * 2 + (i >> 5);
        wcol[i] = 0.125f * W_gat[k * 256 + hh * 32 + c];
    }
    float bg = b_gat[c];
    const float4* z4 = (const float4*)z;
    for (int it = 0; it < 8; ++it) {
        int n = nset * 8 + it;
        if (n >= N) break;
        float p = 0.0f;
        #pragma unroll
        for (int k4 = 0; k4 < 16; ++k4) {
            float4 zv = z4[(size_t)n * 64 + sl * 16 + k4];
            p += zv.x * wcol[4 * k4] + zv.y * wcol[4 * k4 + 1]
               + zv.z * wcol[4 * k4 + 2] + zv.w * wcol[4 * k4 + 3];
        }
        p += __shfl_xor(p, 16, 64);
        p += __shfl_xor(p, 32, 64);
        if (lane < 16) {
            int b = n / n_node, kk = n - b * n_node;
            gatT[((size_t)b * 32 + c) * n_node + kk] = p + bg;
        }
    }
}

// ---------------- K6a: transpose W_ih1 [128][n_node] -> Wt [n_node][128] ----------------
__global__ __launch_bounds__(256) void k_wt(const float* __restrict__ W,
                                            float* __restrict__ Wt, int n_node) {
    __shared__ float tle[32][33];
    int kt = blockIdx.x & 31;
    int gt = blockIdx.x >> 5;
    int tid = threadIdx.x;
    for (int i = tid; i < 1024; i += 256) {
        int gl = i >> 5, kl = i & 31;
        int g = gt * 32 + gl, k = kt * 32 + kl;
        tle[gl][kl] = (k < n_node) ? W[(size_t)g * n_node + k] : 0.0f;
    }
    __syncthreads();
    for (int i = tid; i < 1024; i += 256) {
        int kl = i >> 5, gl = i & 31;
        int k = kt * 32 + kl, g = gt * 32 + gl;
        if (k < n_node) Wt[(size_t)k * 128 + g] = tle[gl][kl];
    }
}

// ---------------- K6c: pack LSTM weights, full-row pair layout ----------------
// k_lstm thread t (0..255): unit u = t>>1, half ht = t&1; owns rows
//   r(p) = ht*256 + p*128 + u, p in {0,1}  (ht=0: {i,f} rows; ht=1: {g,o} rows)
// wc2p[(p*16+j)*256 + t] (uint4 fp16x8), j in [0,16): W_hh2[r(p)][j*8..+8)
// wi2p[(p*4+j)*256 + t]  (uint4 fp16x8), j in [0,4):  W_ih2[r(p)][j*8..+8)
// w1p [(p*4+j)*64 + l]   (uint4 fp16x8), l in [0,64), rows rA=l (p=0), rB=64+l (p=1):
//     W_hh1[r][j*8..+8)
__global__ __launch_bounds__(256) void k_pack2(
    const float* __restrict__ W_hh2, const float* __restrict__ W_ih2,
    const float* __restrict__ W_hh1,
    uint4* __restrict__ wc2p, uint4* __restrict__ wi2p, uint4* __restrict__ w1p) {
    int i = blockIdx.x * 256 + threadIdx.x;
    __align__(16) _Float16 tmp[8];
    if (i < 8192) {
        int jj = i >> 8, t = i & 255;
        int p = jj >> 4, j = jj & 15;
        int r = (t & 1) * 256 + p * 128 + (t >> 1);
        const float* s = W_hh2 + (size_t)r * 128 + j * 8;
        #pragma unroll
        for (int k = 0; k < 8; ++k) tmp[k] = (_Float16)s[k];
        wc2p[jj * 256 + t] = *(const uint4*)tmp;
    } else if (i < 10240) {
        int ii = i - 8192;
        int jj = ii >> 8, t = ii & 255;
        int p = jj >> 2, j = jj & 3;
        int r = (t & 1) * 256 + p * 128 + (t >> 1);
        const float* s = W_ih2 + (size_t)r * 32 + j * 8;
        #pragma unroll
        for (int k = 0; k < 8; ++k) tmp[k] = (_Float16)s[k];
        wi2p[jj * 256 + t] = *(const uint4*)tmp;
    } else if (i < 10752) {
        int ii = i - 10240;
        int jj = ii >> 6, l = ii & 63;
        int p = jj >> 2, j = jj & 3;
        int r = p * 64 + l;
        const float* s = W_hh1 + (size_t)r * 32 + j * 8;
        #pragma unroll
        for (int k = 0; k < 8; ++k) tmp[k] = (_Float16)s[k];
        w1p[jj * 64 + l] = *(const uint4*)tmp;
    }
}

// ---------------- K6b: P1[t,b,g] = bias + dot(Wt[:, g], gatT[b][t][:]) ----------------
__global__ __launch_bounds__(256) void k_p1(
    const float* __restrict__ gatT, const float* __restrict__ Wt,
    const float* __restrict__ b_ih1, const float* __restrict__ b_hh1,
    float* __restrict__ P1, int n_node, int B) {
    __shared__ __align__(16) float Arow[2][1024];
    __shared__ __align__(16) float part[4][2][128];
    int blk = blockIdx.x;
    int b = blk >> 4;
    int tq = blk & 15;
    int tid = threadIdx.x;
    const float* A0 = gatT + ((size_t)b * 32 + tq * 2) * n_node;
    #pragma unroll
    for (int r = 0; r < 2; ++r)
        for (int i = tid; i < n_node; i += 256)
            Arow[r][i] = A0[(size_t)r * n_node + i];
    __syncthreads();

    int g4 = tid & 31;
    int tloc = (tid >> 5) & 1;
    int ks = tid >> 6;
    int kq = n_node >> 2;            // 250
    int k0 = ks * kq;
    const float4* Wt4 = (const float4*)Wt;
    float4 acc = make_float4(0.0f, 0.0f, 0.0f, 0.0f);
    #pragma unroll 4
    for (int k = 0; k < kq; ++k) {
        float4 w = Wt4[(size_t)(k0 + k) * 32 + g4];
        float a = Arow[tloc][k0 + k];
        acc.x += w.x * a; acc.y += w.y * a;
        acc.z += w.z * a; acc.w += w.w * a;
    }
    *(float4*)&part[ks][tloc][g4 * 4] = acc;
    __syncthreads();

    int tl = tid >> 7, g = tid & 127;
    float s = part[0][tl][g] + part[1][tl][g] + part[2][tl][g] + part[3][tl][g]
            + b_ih1[g] + b_hh1[g];
    int t = tq * 2 + tl;
    P1[((size_t)t * B + b) * 128 + g] = s;
}

// ---------------- K7: pipelined LSTM1 || LSTM2, 4-wave full-row ----------------
// 256 threads = 4 waves, __launch_bounds__(256,1) -> up to 512 VGPR, no spill
// possible (~180 live). Thread t owns 2 FULL gate rows of unit u=t>>1
// (ht=t&1 selects {i,f} or {g,o}): weights 2x(128+32) fp16 = 112 VGPR resident.
// Per step: 20 broadcast LDS reads, 160 v_dot2, 2 shfl_xor(1) to swap gate
// pairs (partner thread = t^1), pointwise computed redundantly by both halves.
// LSTM1 on wave 0 only (2 rows/lane: l and 64+l; 1 shfl_xor(32) exchange).
// Lag pipeline: superstep s runs L2 step t2=s-1 and L1 step s concurrently.
// Parity: h1[k] -> h1buf[(k+1)&1]; h2[k] -> h2buf[(k+1)&1].
//   L2 at s: reads h2buf[(s-1)&1] (=h2[s-2]), h1buf[s&1] (=h1[s-1]),
//            writes h2buf[s&1]. L1 at s: reads h1buf[s&1], writes h1buf[(s+1)&1].
__global__ __launch_bounds__(256, 1) void k_lstm(
    const float* __restrict__ P1, const uint4* __restrict__ wc2p,
    const uint4* __restrict__ wi2p, const uint4* __restrict__ w1p,
    const float* __restrict__ b_ih2, const float* __restrict__ b_hh2,
    float* __restrict__ h2finT, int B, int T) {
    __shared__ __align__(16) float P1s[32][128];     // 16KB
    __shared__ __align__(16) __half h1buf[2][32];    // fp16 L1 state, dbuf
    __shared__ __align__(16) __half h2buf[2][128];   // fp16 L2 state, dbuf
    int t = threadIdx.x, b = blockIdx.x;
    int u = t >> 1, ht = t & 1;

    // stage P1
    for (int i = t; i < 1024; i += 256) {
        int tt = i >> 5, c4 = i & 31;
        ((float4*)P1s[tt])[c4] = ((const float4*)(P1 + ((size_t)tt * B + b) * 128))[c4];
    }
    // weights: coalesced preload
    uint4 wc[32];
    #pragma unroll
    for (int j = 0; j < 32; ++j) wc[j] = wc2p[j * 256 + t];
    uint4 wi[8];
    #pragma unroll
    for (int j = 0; j < 8; ++j) wi[j] = wi2p[j * 256 + t];
    uint4 w1[8];
    if (t < 64) {
        #pragma unroll
        for (int j = 0; j < 8; ++j) w1[j] = w1p[j * 64 + t];
    }
    int r0 = ht * 256 + u;            // row p=0
    int r1 = ht * 256 + 128 + u;      // row p=1
    float bias0 = b_ih2[r0] + b_hh2[r0];
    float bias1 = b_ih2[r1] + b_hh2[r1];

    // init state
    if (t < 32) h1buf[0][t] = __float2half(0.0f);
    if (t < 128) h2buf[0][t] = __float2half(0.0f);
    float c1 = 0.0f, c2 = 0.0f;
    __syncthreads();

    for (int s = 0; s <= T; ++s) {
        // shared h1 read: h1buf[s&1] = h1[s-1] (zeros at s=0)
        const uint4* h1q = (const uint4*)h1buf[s & 1];
        uint4 hv0 = h1q[0], hv1 = h1q[1], hv2 = h1q[2], hv3 = h1q[3];

        // ---- LSTM2 step t2 = s-1 (all threads) ----
        if (s >= 1) {
            int t2 = s - 1;
            const uint4* hb = (const uint4*)h2buf[t2 & 1];
            // input projection (fp16 dot2): rows p=0,1
            float p0a, p0b, p1a, p1b;
            p0a = dot16(wi[0], hv0, 0.0f); p0b = dot16(wi[1], hv1, 0.0f);
            p0a = dot16(wi[2], hv2, p0a);  p0b = dot16(wi[3], hv3, p0b);
            p1a = dot16(wi[4], hv0, 0.0f); p1b = dot16(wi[5], hv1, 0.0f);
            p1a = dot16(wi[6], hv2, p1a);  p1b = dot16(wi[7], hv3, p1b);
            // recurrent 128-dot, chunked h2 reads (4 uint4 live at a time)
            #pragma unroll
            for (int c = 0; c < 4; ++c) {
                uint4 h0 = hb[c * 4], h1_ = hb[c * 4 + 1];
                uint4 h2_ = hb[c * 4 + 2], h3 = hb[c * 4 + 3];
                p0a = dot16(wc[c * 4], h0, p0a);
                p0b = dot16(wc[c * 4 + 1], h1_, p0b);
                p0a = dot16(wc[c * 4 + 2], h2_, p0a);
                p0b = dot16(wc[c * 4 + 3], h3, p0b);
                p1a = dot16(wc[16 + c * 4], h0, p1a);
                p1b = dot16(wc[16 + c * 4 + 1], h1_, p1b);
                p1a = dot16(wc[16 + c * 4 + 2], h2_, p1a);
                p1b = dot16(wc[16 + c * 4 + 3], h3, p1b);
            }
            float s0 = p0a + p0b + bias0;   // ht=0: gate i | ht=1: gate g
            float s1 = p1a + p1b + bias1;   // ht=0: gate f | ht=1: gate o
            float o0 = __shfl_xor(s0, 1, 64);
            float o1 = __shfl_xor(s1, 1, 64);
            float gi = (ht == 0) ? s0 : o0;
            float gf = (ht == 0) ? s1 : o1;
            float gg = (ht == 0) ? o0 : s0;
            float go = (ht == 0) ? o1 : s1;
            c2 = sigm(gf) * c2 + sigm(gi) * tanh_fast(gg);
            float h = sigm(go) * tanh_fast(c2);
            if (ht == 0) {
                h2buf[(t2 + 1) & 1][u] = __float2half(h);
                if (t2 == T - 1) h2finT[u * 32 + b] = h;
            }
        }
        // ---- LSTM1 step s (wave 0 only) ----
        if (t < 64 && s < T) {
            float aA = P1s[s][t];        // row l  (l<32: gate i of unit l; l>=32: gate f of unit l-32)
            float aB = P1s[s][64 + t];   // row 64+l (gate g / gate o)
            aA = dot16(w1[0], hv0, aA); aA = dot16(w1[1], hv1, aA);
            aA = dot16(w1[2], hv2, aA); aA = dot16(w1[3], hv3, aA);
            aB = dot16(w1[4], hv0, aB); aB = dot16(w1[5], hv1, aB);
            aB = dot16(w1[6], hv2, aB); aB = dot16(w1[7], hv3, aB);
            float oA = __shfl_xor(aA, 32, 64);
            float oB = __shfl_xor(aB, 32, 64);
            float gi = (t < 32) ? aA : oA;
            float gf = (t < 32) ? oA : aA;
            float gg = (t < 32) ? aB : oB;
            float go = (t < 32) ? oB : aB;
            c1 = sigm(gf) * c1 + sigm(gi) * tanh_fast(gg);
            float h = sigm(go) * tanh_fast(c1);
            if (t < 32) h1buf[(s + 1) & 1][t] = __float2half(h);
        }
        __syncthreads();
    }
}

// ---------------- K8: final linear from h2finT ----------------
__global__ __launch_bounds__(256) void k_fin(
    const float* __restrict__ h2finT, const float* __restrict__ W_lin,
    const float* __restrict__ b_lin, float* __restrict__ out, int n_node, int B) {
    __shared__ __align__(16) float hs[128];
    int b = blockIdx.x >> 3;
    int kc = blockIdx.x & 7;
    int tid = threadIdx.x;
    if (tid < 128) hs[tid] = h2finT[tid * 32 + b];
    __syncthreads();
    int outdim = n_node * 2;
    int kk = kc * 256 + tid;
    if (kk < outdim) {
        float acc = b_lin[kk];
        const float4* W4 = (const float4*)(W_lin + (size_t)kk * 128);
        const float4* h4 = (const float4*)hs;
        #pragma unroll 8
        for (int j = 0; j < 32; ++j) {
            float4 w = W4[j], h = h4[j];
            acc += w.x * h.x + w.y * h.y + w.z * h.z + w.w * h.w;
        }
        out[(size_t)b * outdim + kk] = acc;
    }
}

extern "C" void kernel_launch(void* const* d_in, const int* in_sizes, int n_in,
                              void* d_out, int out_size, void* d_ws, size_t ws_size,
                              hipStream_t stream) {
    const float* x     = (const float*)d_in[0];
    const int*   src   = (const int*)d_in[1];
    const int*   dst   = (const int*)d_in[2];
    const float* W_gat = (const float*)d_in[4];
    const float* a_src = (const float*)d_in[5];
    const float* a_dst = (const float*)d_in[6];
    const float* b_gat = (const float*)d_in[7];
    const float* W_ih1 = (const float*)d_in[8];
    const float* W_hh1 = (const float*)d_in[9];
    const float* b_ih1 = (const float*)d_in[10];
    const float* b_hh1 = (const float*)d_in[11];
    const float* W_ih2 = (const float*)d_in[12];
    const float* W_hh2 = (const float*)d_in[13];
    const float* b_ih2 = (const float*)d_in[14];
    const float* b_hh2 = (const float*)d_in[15];
    const float* W_lin = (const float*)d_in[16];
    const float* b_lin = (const float*)d_in[17];

    int N = in_sizes[0] / 32;          // 32000
    int E = in_sizes[1];               // 384000
    int n_node = in_sizes[8] / 128;    // 1000
    int B = N / n_node;                // 32
    int T = 32;

    float* ws = (float*)d_ws;
    float* z      = ws;                                 // N*256
    float* asrc   = z + (size_t)N * 256;                // N*8
    float* adst   = asrc + (size_t)N * 8;               // N*8
    float* gatT   = adst + (size_t)N * 8;               // N*32
    float* P1     = gatT + (size_t)N * 32;              // T*B*128
    float* wc2f   = P1 + (size_t)T * B * 128;           // 8192 uint4 = 32768 f32
    float* wiff   = wc2f + 32768;                       // 2048 uint4 = 8192 f32
    float* w1ff   = wiff + 8192;                        // 512 uint4 = 2048 f32
    float* h2finT = w1ff + 2048;                        // 128*32
    float* wa     = h2finT + 128 * 32;                  // 512
    int* deg     = (int*)(wa + 512);                    // N
    int* cursor  = deg + N;                             // N
    int* rowptr  = cursor + N;                          // N+1
    int* csr_src = rowptr + N + 1;                      // E
    int* blksum  = csr_src + E;                         // 256
    int* blkoff  = blksum + 256;                        // 256
    float* Wt    = (float*)(((uintptr_t)(blkoff + 256) + 255) & ~(uintptr_t)255); // n_node*128

    uint4* wc2p = (uint4*)wc2f;
    uint4* wi2p = (uint4*)wiff;
    uint4* w1p  = (uint4*)w1ff;

    int nb = (N + 255) / 256;   // 125

    k_pack2<<<42, 256, 0, stream>>>(W_hh2, W_ih2, W_hh1, wc2p, wi2p, w1p);
    k_wt<<<128, 256, 0, stream>>>(W_ih1, Wt, n_node);
    k_zero<<<(N + 255) / 256, 256, 0, stream>>>(deg, N);
    k_hist<<<(E + 255) / 256, 256, 0, stream>>>(dst, deg, E);
    k_scan1<<<nb, 256, 0, stream>>>(deg, blksum, N);
    k_scan2<<<1, 256, 0, stream>>>(blksum, blkoff, nb);
    k_scan3<<<nb, 256, 0, stream>>>(deg, blkoff, rowptr, cursor, N, E);
    k_scatter<<<(E + 255) / 256, 256, 0, stream>>>(src, dst, cursor, csr_src, E);
    k_pre<<<1, 256, 0, stream>>>(W_gat, a_src, a_dst, wa);
    k_att<<<N / 32, 256, 0, stream>>>(x, wa, asrc, adst);
    k_gat<<<(N * 64 + 255) / 256, 256, 0, stream>>>(rowptr, csr_src, asrc, adst,
                                                    x, z, N);
    k_zw<<<2000, 256, 0, stream>>>(z, W_gat, b_gat, gatT, N, n_node);
    k_p1<<<B * 16, 256, 0, stream>>>(gatT, Wt, b_ih1, b_hh1, P1, n_node, B);
    k_lstm<<<B, 256, 0, stream>>>(P1, wc2p, wi2p, w1p, b_ih2, b_hh2, h2finT, B, T);
    k_fin<<<B * 8, 256, 0, stream>>>(h2finT, W_lin, b_lin, (float*)d_out, n_node, B);
}

// Round 9
// 204.341 us; speedup vs baseline: 1.1780x; 1.0798x over previous
//
#include <hip/hip_runtime.h>
#include <hip/hip_fp16.h>
#include <math.h>

#define NEG_SLOPE 0.2f

__device__ __forceinline__ float sigm(float x) { return 1.0f / (1.0f + __expf(-x)); }
__device__ __forceinline__ float tanh_fast(float x) {
    float xc = fminf(fmaxf(x, -15.0f), 15.0f);
    float e2 = __expf(2.0f * xc);
    return (e2 - 1.0f) / (e2 + 1.0f);
}
__device__ __forceinline__ float lrelu(float x) { return (x > 0.0f) ? x : NEG_SLOPE * x; }

typedef _Float16 h2v __attribute__((ext_vector_type(2)));
__device__ __forceinline__ float fdot2h(h2v a, h2v b, float c) {
#if __has_builtin(__builtin_amdgcn_fdot2)
    return __builtin_amdgcn_fdot2(a, b, c, false);
#else
    return (float)a[0] * (float)b[0] + (float)a[1] * (float)b[1] + c;
#endif
}

// dot over 8 fp16 dims held as uint4 (4 x v_dot2)
__device__ __forceinline__ float dot16(const uint4& w, const uint4& h, float acc) {
    const h2v* wp = reinterpret_cast<const h2v*>(&w);
    const h2v* hp = reinterpret_cast<const h2v*>(&h);
    acc = fdot2h(wp[0], hp[0], acc);
    acc = fdot2h(wp[1], hp[1], acc);
    acc = fdot2h(wp[2], hp[2], acc);
    acc = fdot2h(wp[3], hp[3], acc);
    return acc;
}

// ---------------- K0: zero deg ----------------
__global__ void k_zero(int* __restrict__ deg, int N) {
    int i = blockIdx.x * 256 + threadIdx.x;
    if (i < N) deg[i] = 0;
}

// ---------------- K1: histogram of dst ----------------
__global__ void k_hist(const int* __restrict__ dst, int* __restrict__ deg, int E) {
    int e = blockIdx.x * 256 + threadIdx.x;
    if (e < E) atomicAdd(deg + dst[e], 1);
}

// ---------------- scan (3 kernels, multi-block) ----------------
__global__ __launch_bounds__(256) void k_scan1(const int* __restrict__ deg,
                                               int* __restrict__ blksum, int N) {
    __shared__ int s[256];
    int tid = threadIdx.x;
    int i = blockIdx.x * 256 + tid;
    int v = (i < N) ? deg[i] : 0;
    s[tid] = v;
    __syncthreads();
    #pragma unroll
    for (int off = 128; off > 0; off >>= 1) {
        if (tid < off) s[tid] += s[tid + off];
        __syncthreads();
    }
    if (tid == 0) blksum[blockIdx.x] = s[0];
}

__global__ __launch_bounds__(256) void k_scan2(const int* __restrict__ blksum,
                                               int* __restrict__ blkoff, int nb) {
    __shared__ int s[256];
    int tid = threadIdx.x;
    int v = (tid < nb) ? blksum[tid] : 0;
    s[tid] = v;
    __syncthreads();
    for (int off = 1; off < 256; off <<= 1) {
        int t = (tid >= off) ? s[tid - off] : 0;
        __syncthreads();
        s[tid] += t;
        __syncthreads();
    }
    if (tid < nb) blkoff[tid] = s[tid] - v;   // exclusive
}

__global__ __launch_bounds__(256) void k_scan3(const int* __restrict__ deg,
                                               const int* __restrict__ blkoff,
                                               int* __restrict__ rowptr,
                                               int* __restrict__ cursor, int N, int E) {
    __shared__ int s[256];
    int tid = threadIdx.x;
    int i = blockIdx.x * 256 + tid;
    int v = (i < N) ? deg[i] : 0;
    s[tid] = v;
    __syncthreads();
    for (int off = 1; off < 256; off <<= 1) {
        int t = (tid >= off) ? s[tid - off] : 0;
        __syncthreads();
        s[tid] += t;
        __syncthreads();
    }
    int excl = s[tid] - v + blkoff[blockIdx.x];
    if (i < N) { rowptr[i] = excl; cursor[i] = excl; }
    if (i == N - 1) rowptr[N] = E;
}

// ---------------- K3: scatter edges into CSR (by dst) ----------------
__global__ void k_scatter(const int* __restrict__ src, const int* __restrict__ dst,
                          int* __restrict__ cursor, int* __restrict__ csr_src, int E) {
    int e = blockIdx.x * 256 + threadIdx.x;
    if (e < E) {
        int pos = atomicAdd(cursor + dst[e], 1);
        csr_src[pos] = src[e];
    }
}

// ---------------- K4a: wa_src[k][h] ----------------
__global__ void k_pre(const float* __restrict__ W_gat, const float* __restrict__ a_src,
                      const float* __restrict__ a_dst, float* __restrict__ wa) {
    int tid = threadIdx.x;          // tid = k*8 + h
    int k = tid >> 3, h = tid & 7;
    float s1 = 0.0f, s2 = 0.0f;
    for (int c = 0; c < 32; ++c) {
        float wv = W_gat[k * 256 + h * 32 + c];
        s1 += wv * a_src[h * 32 + c];
        s2 += wv * a_dst[h * 32 + c];
    }
    wa[tid] = s1;
    wa[256 + tid] = s2;
}

// ---------------- K4b: asrc/adst = x @ wa ----------------
__global__ __launch_bounds__(256) void k_att(const float* __restrict__ x,
                                             const float* __restrict__ wa,
                                             float* __restrict__ asrc,
                                             float* __restrict__ adst) {
    __shared__ float xs[32 * 33];
    __shared__ float was[256], wad[256];
    int tid = threadIdx.x;
    int n0 = blockIdx.x * 32;
    for (int i = tid; i < 1024; i += 256) {
        int nl = i >> 5, k = i & 31;
        xs[nl * 33 + k] = x[(size_t)(n0 + nl) * 32 + k];
    }
    was[tid] = wa[tid];
    wad[tid] = wa[256 + tid];
    __syncthreads();
    int nl = tid >> 3, h = tid & 7;
    float s1 = 0.0f, s2 = 0.0f;
    #pragma unroll
    for (int k = 0; k < 32; ++k) {
        float xv = xs[nl * 33 + k];
        s1 += xv * was[k * 8 + h];
        s2 += xv * wad[k * 8 + h];
    }
    asrc[(size_t)(n0 + nl) * 8 + h] = s1;
    adst[(size_t)(n0 + nl) * 8 + h] = s2;
}

// ---------------- K5: GAT gather, 8-deep MLP chunks ----------------
// One wave per dst node. Edges processed in chunks of 8: all 8 csr loads
// issue independently, then all 16 dependent asrc/x loads issue together
// (24 VMEM in flight) -> latency overlapped ~8x vs serial chain. Tail is
// branch-free: surplus slots clamp to s0 and mask ew to 0.
__global__ __launch_bounds__(256) void k_gat(
    const int* __restrict__ rowptr, const int* __restrict__ csr_src,
    const float* __restrict__ asrc, const float* __restrict__ adst,
    const float* __restrict__ x, float* __restrict__ z, int N) {
    int w = (blockIdx.x * 256 + threadIdx.x) >> 6;
    int lane = threadIdx.x & 63;
    if (w >= N) return;
    int r0 = rowptr[w], r1 = rowptr[w + 1];
    int h = lane >> 3, kq = lane & 7;
    float ad = adst[w * 8 + h];
    float4 acc = make_float4(0.0f, 0.0f, 0.0f, 0.0f);
    float den = 0.0f;
    const float4* x4 = (const float4*)x;
    for (int i = r0; i < r1; i += 8) {
        int rem = r1 - i;
        int s0 = csr_src[i];
        int s1 = (rem > 1) ? csr_src[i + 1] : s0;
        int s2 = (rem > 2) ? csr_src[i + 2] : s0;
        int s3 = (rem > 3) ? csr_src[i + 3] : s0;
        int s4 = (rem > 4) ? csr_src[i + 4] : s0;
        int s5 = (rem > 5) ? csr_src[i + 5] : s0;
        int s6 = (rem > 6) ? csr_src[i + 6] : s0;
        int s7 = (rem > 7) ? csr_src[i + 7] : s0;
        float a0 = asrc[s0 * 8 + h], a1 = asrc[s1 * 8 + h];
        float a2 = asrc[s2 * 8 + h], a3 = asrc[s3 * 8 + h];
        float a4 = asrc[s4 * 8 + h], a5 = asrc[s5 * 8 + h];
        float a6 = asrc[s6 * 8 + h], a7 = asrc[s7 * 8 + h];
        float4 v0 = x4[(size_t)s0 * 8 + kq], v1 = x4[(size_t)s1 * 8 + kq];
        float4 v2 = x4[(size_t)s2 * 8 + kq], v3 = x4[(size_t)s3 * 8 + kq];
        float4 v4 = x4[(size_t)s4 * 8 + kq], v5 = x4[(size_t)s5 * 8 + kq];
        float4 v6 = x4[(size_t)s6 * 8 + kq], v7 = x4[(size_t)s7 * 8 + kq];
        float e0 = __expf(lrelu(a0 + ad));
        float e1 = (rem > 1) ? __expf(lrelu(a1 + ad)) : 0.0f;
        float e2 = (rem > 2) ? __expf(lrelu(a2 + ad)) : 0.0f;
        float e3 = (rem > 3) ? __expf(lrelu(a3 + ad)) : 0.0f;
        float e4 = (rem > 4) ? __expf(lrelu(a4 + ad)) : 0.0f;
        float e5 = (rem > 5) ? __expf(lrelu(a5 + ad)) : 0.0f;
        float e6 = (rem > 6) ? __expf(lrelu(a6 + ad)) : 0.0f;
        float e7 = (rem > 7) ? __expf(lrelu(a7 + ad)) : 0.0f;
        acc.x += e0 * v0.x + e1 * v1.x + e2 * v2.x + e3 * v3.x
               + e4 * v4.x + e5 * v5.x + e6 * v6.x + e7 * v7.x;
        acc.y += e0 * v0.y + e1 * v1.y + e2 * v2.y + e3 * v3.y
               + e4 * v4.y + e5 * v5.y + e6 * v6.y + e7 * v7.y;
        acc.z += e0 * v0.z + e1 * v1.z + e2 * v2.z + e3 * v3.z
               + e4 * v4.z + e5 * v5.z + e6 * v6.z + e7 * v7.z;
        acc.w += e0 * v0.w + e1 * v1.w + e2 * v2.w + e3 * v3.w
               + e4 * v4.w + e5 * v5.w + e6 * v6.w + e7 * v7.w;
        den += ((e0 + e1) + (e2 + e3)) + ((e4 + e5) + (e6 + e7));
    }
    float inv = 1.0f / fmaxf(den, 1e-16f);
    float4 r = make_float4(acc.x * inv, acc.y * inv, acc.z * inv, acc.w * inv);
    ((float4*)z)[(size_t)w * 64 + lane] = r;
}

// ---------------- K5b: gatT[b][c][node] = z[node,:] @ M[:,c] + b_gat[c] ----------------
__global__ __launch_bounds__(256) void k_zw(
    const float* __restrict__ z, const float* __restrict__ W_gat,
    const float* __restrict__ b_gat, float* __restrict__ gatT, int N, int n_node) {
    int gw = (blockIdx.x * 256 + threadIdx.x) >> 6;  // 0..7999
    int lane = threadIdx.x & 63;
    int chalf = gw & 1;
    int nset = gw >> 1;                               // 0..3999
    int c = chalf * 16 + (lane & 15);
    int sl = lane >> 4;
    float wcol[64];
    #pragma unroll
    for (int i = 0; i < 64; ++i) {
        int k = i & 31, hh = sl * 2 + (i >> 5);
        wcol[i] = 0.125f * W_gat[k * 256 + hh * 32 + c];
    }
    float bg = b_gat[c];
    const float4* z4 = (const float4*)z;
    for (int it = 0; it < 8; ++it) {
        int n = nset * 8 + it;
        if (n >= N) break;
        float p = 0.0f;
        #pragma unroll
        for (int k4 = 0; k4 < 16; ++k4) {
            float4 zv = z4[(size_t)n * 64 + sl * 16 + k4];
            p += zv.x * wcol[4 * k4] + zv.y * wcol[4 * k4 + 1]
               + zv.z * wcol[4 * k4 + 2] + zv.w * wcol[4 * k4 + 3];
        }
        p += __shfl_xor(p, 16, 64);
        p += __shfl_xor(p, 32, 64);
        if (lane < 16) {
            int b = n / n_node, kk = n - b * n_node;
            gatT[((size_t)b * 32 + c) * n_node + kk] = p + bg;
        }
    }
}

// ---------------- K6a: transpose W_ih1 [128][n_node] -> Wt [n_node][128] ----------------
__global__ __launch_bounds__(256) void k_wt(const float* __restrict__ W,
                                            float* __restrict__ Wt, int n_node) {
    __shared__ float tle[32][33];
    int kt = blockIdx.x & 31;
    int gt = blockIdx.x >> 5;
    int tid = threadIdx.x;
    for (int i = tid; i < 1024; i += 256) {
        int gl = i >> 5, kl = i & 31;
        int g = gt * 32 + gl, k = kt * 32 + kl;
        tle[gl][kl] = (k < n_node) ? W[(size_t)g * n_node + k] : 0.0f;
    }
    __syncthreads();
    for (int i = tid; i < 1024; i += 256) {
        int kl = i >> 5, gl = i & 31;
        int k = kt * 32 + kl, g = gt * 32 + gl;
        if (k < n_node) Wt[(size_t)k * 128 + g] = tle[gl][kl];
    }
}

// ---------------- K6c: pack LSTM weights, full-row pair layout ----------------
// k_lstm thread t (0..255): unit u = t>>1, half ht = t&1; owns rows
//   r(p) = ht*256 + p*128 + u, p in {0,1}  (ht=0: {i,f} rows; ht=1: {g,o} rows)
// wc2p[(p*16+j)*256 + t] (uint4 fp16x8), j in [0,16): W_hh2[r(p)][j*8..+8)
// wi2p[(p*4+j)*256 + t]  (uint4 fp16x8), j in [0,4):  W_ih2[r(p)][j*8..+8)
// w1p [(p*4+j)*64 + l]   (uint4 fp16x8), l in [0,64), rows rA=l (p=0), rB=64+l (p=1):
//     W_hh1[r][j*8..+8)
__global__ __launch_bounds__(256) void k_pack2(
    const float* __restrict__ W_hh2, const float* __restrict__ W_ih2,
    const float* __restrict__ W_hh1,
    uint4* __restrict__ wc2p, uint4* __restrict__ wi2p, uint4* __restrict__ w1p) {
    int i = blockIdx.x * 256 + threadIdx.x;
    __align__(16) _Float16 tmp[8];
    if (i < 8192) {
        int jj = i >> 8, t = i & 255;
        int p = jj >> 4, j = jj & 15;
        int r = (t & 1) * 256 + p * 128 + (t >> 1);
        const float* s = W_hh2 + (size_t)r * 128 + j * 8;
        #pragma unroll
        for (int k = 0; k < 8; ++k) tmp[k] = (_Float16)s[k];
        wc2p[jj * 256 + t] = *(const uint4*)tmp;
    } else if (i < 10240) {
        int ii = i - 8192;
        int jj = ii >> 8, t = ii & 255;
        int p = jj >> 2, j = jj & 3;
        int r = (t & 1) * 256 + p * 128 + (t >> 1);
        const float* s = W_ih2 + (size_t)r * 32 + j * 8;
        #pragma unroll
        for (int k = 0; k < 8; ++k) tmp[k] = (_Float16)s[k];
        wi2p[jj * 256 + t] = *(const uint4*)tmp;
    } else if (i < 10752) {
        int ii = i - 10240;
        int jj = ii >> 6, l = ii & 63;
        int p = jj >> 2, j = jj & 3;
        int r = p * 64 + l;
        const float* s = W_hh1 + (size_t)r * 32 + j * 8;
        #pragma unroll
        for (int k = 0; k < 8; ++k) tmp[k] = (_Float16)s[k];
        w1p[jj * 64 + l] = *(const uint4*)tmp;
    }
}

// ---------------- K6b: P1[t,b,g] = bias + dot(Wt[:, g], gatT[b][t][:]) ----------------
__global__ __launch_bounds__(256) void k_p1(
    const float* __restrict__ gatT, const float* __restrict__ Wt,
    const float* __restrict__ b_ih1, const float* __restrict__ b_hh1,
    float* __restrict__ P1, int n_node, int B) {
    __shared__ __align__(16) float Arow[2][1024];
    __shared__ __align__(16) float part[4][2][128];
    int blk = blockIdx.x;
    int b = blk >> 4;
    int tq = blk & 15;
    int tid = threadIdx.x;
    const float* A0 = gatT + ((size_t)b * 32 + tq * 2) * n_node;
    #pragma unroll
    for (int r = 0; r < 2; ++r)
        for (int i = tid; i < n_node; i += 256)
            Arow[r][i] = A0[(size_t)r * n_node + i];
    __syncthreads();

    int g4 = tid & 31;
    int tloc = (tid >> 5) & 1;
    int ks = tid >> 6;
    int kq = n_node >> 2;            // 250
    int k0 = ks * kq;
    const float4* Wt4 = (const float4*)Wt;
    float4 acc = make_float4(0.0f, 0.0f, 0.0f, 0.0f);
    #pragma unroll 4
    for (int k = 0; k < kq; ++k) {
        float4 w = Wt4[(size_t)(k0 + k) * 32 + g4];
        float a = Arow[tloc][k0 + k];
        acc.x += w.x * a; acc.y += w.y * a;
        acc.z += w.z * a; acc.w += w.w * a;
    }
    *(float4*)&part[ks][tloc][g4 * 4] = acc;
    __syncthreads();

    int tl = tid >> 7, g = tid & 127;
    float s = part[0][tl][g] + part[1][tl][g] + part[2][tl][g] + part[3][tl][g]
            + b_ih1[g] + b_hh1[g];
    int t = tq * 2 + tl;
    P1[((size_t)t * B + b) * 128 + g] = s;
}

// ---------------- K7: pipelined LSTM1 || LSTM2, 4-wave full-row ----------------
// (unchanged from R8 — proven at absmax 1.2e-4)
__global__ __launch_bounds__(256, 1) void k_lstm(
    const float* __restrict__ P1, const uint4* __restrict__ wc2p,
    const uint4* __restrict__ wi2p, const uint4* __restrict__ w1p,
    const float* __restrict__ b_ih2, const float* __restrict__ b_hh2,
    float* __restrict__ h2finT, int B, int T) {
    __shared__ __align__(16) float P1s[32][128];     // 16KB
    __shared__ __align__(16) __half h1buf[2][32];    // fp16 L1 state, dbuf
    __shared__ __align__(16) __half h2buf[2][128];   // fp16 L2 state, dbuf
    int t = threadIdx.x, b = blockIdx.x;
    int u = t >> 1, ht = t & 1;

    // stage P1
    for (int i = t; i < 1024; i += 256) {
        int tt = i >> 5, c4 = i & 31;
        ((float4*)P1s[tt])[c4] = ((const float4*)(P1 + ((size_t)tt * B + b) * 128))[c4];
    }
    // weights: coalesced preload
    uint4 wc[32];
    #pragma unroll
    for (int j = 0; j < 32; ++j) wc[j] = wc2p[j * 256 + t];
    uint4 wi[8];
    #pragma unroll
    for (int j = 0; j < 8; ++j) wi[j] = wi2p[j * 256 + t];
    uint4 w1[8];
    if (t < 64) {
        #pragma unroll
        for (int j = 0; j < 8; ++j) w1[j] = w1p[j * 64 + t];
    }
    int r0 = ht * 256 + u;            // row p=0
    int r1 = ht * 256 + 128 + u;      // row p=1
    float bias0 = b_ih2[r0] + b_hh2[r0];
    float bias1 = b_ih2[r1] + b_hh2[r1];

    // init state
    if (t < 32) h1buf[0][t] = __float2half(0.0f);
    if (t < 128) h2buf[0][t] = __float2half(0.0f);
    float c1 = 0.0f, c2 = 0.0f;
    __syncthreads();

    for (int s = 0; s <= T; ++s) {
        // shared h1 read: h1buf[s&1] = h1[s-1] (zeros at s=0)
        const uint4* h1q = (const uint4*)h1buf[s & 1];
        uint4 hv0 = h1q[0], hv1 = h1q[1], hv2 = h1q[2], hv3 = h1q[3];

        // ---- LSTM2 step t2 = s-1 (all threads) ----
        if (s >= 1) {
            int t2 = s - 1;
            const uint4* hb = (const uint4*)h2buf[t2 & 1];
            // input projection (fp16 dot2): rows p=0,1
            float p0a, p0b, p1a, p1b;
            p0a = dot16(wi[0], hv0, 0.0f); p0b = dot16(wi[1], hv1, 0.0f);
            p0a = dot16(wi[2], hv2, p0a);  p0b = dot16(wi[3], hv3, p0b);
            p1a = dot16(wi[4], hv0, 0.0f); p1b = dot16(wi[5], hv1, 0.0f);
            p1a = dot16(wi[6], hv2, p1a);  p1b = dot16(wi[7], hv3, p1b);
            // recurrent 128-dot, chunked h2 reads (4 uint4 live at a time)
            #pragma unroll
            for (int c = 0; c < 4; ++c) {
                uint4 h0 = hb[c * 4], h1_ = hb[c * 4 + 1];
                uint4 h2_ = hb[c * 4 + 2], h3 = hb[c * 4 + 3];
                p0a = dot16(wc[c * 4], h0, p0a);
                p0b = dot16(wc[c * 4 + 1], h1_, p0b);
                p0a = dot16(wc[c * 4 + 2], h2_, p0a);
                p0b = dot16(wc[c * 4 + 3], h3, p0b);
                p1a = dot16(wc[16 + c * 4], h0, p1a);
                p1b = dot16(wc[16 + c * 4 + 1], h1_, p1b);
                p1a = dot16(wc[16 + c * 4 + 2], h2_, p1a);
                p1b = dot16(wc[16 + c * 4 + 3], h3, p1b);
            }
            float s0 = p0a + p0b + bias0;   // ht=0: gate i | ht=1: gate g
            float s1 = p1a + p1b + bias1;   // ht=0: gate f | ht=1: gate o
            float o0 = __shfl_xor(s0, 1, 64);
            float o1 = __shfl_xor(s1, 1, 64);
            float gi = (ht == 0) ? s0 : o0;
            float gf = (ht == 0) ? s1 : o1;
            float gg = (ht == 0) ? o0 : s0;
            float go = (ht == 0) ? o1 : s1;
            c2 = sigm(gf) * c2 + sigm(gi) * tanh_fast(gg);
            float h = sigm(go) * tanh_fast(c2);
            if (ht == 0) {
                h2buf[(t2 + 1) & 1][u] = __float2half(h);
                if (t2 == T - 1) h2finT[u * 32 + b] = h;
            }
        }
        // ---- LSTM1 step s (wave 0 only) ----
        if (t < 64 && s < T) {
            float aA = P1s[s][t];        // row l  (l<32: gate i of unit l; l>=32: gate f of unit l-32)
            float aB = P1s[s][64 + t];   // row 64+l (gate g / gate o)
            aA = dot16(w1[0], hv0, aA); aA = dot16(w1[1], hv1, aA);
            aA = dot16(w1[2], hv2, aA); aA = dot16(w1[3], hv3, aA);
            aB = dot16(w1[4], hv0, aB); aB = dot16(w1[5], hv1, aB);
            aB = dot16(w1[6], hv2, aB); aB = dot16(w1[7], hv3, aB);
            float oA = __shfl_xor(aA, 32, 64);
            float oB = __shfl_xor(aB, 32, 64);
            float gi = (t < 32) ? aA : oA;
            float gf = (t < 32) ? oA : aA;
            float gg = (t < 32) ? aB : oB;
            float go = (t < 32) ? oB : aB;
            c1 = sigm(gf) * c1 + sigm(gi) * tanh_fast(gg);
            float h = sigm(go) * tanh_fast(c1);
            if (t < 32) h1buf[(s + 1) & 1][t] = __float2half(h);
        }
        __syncthreads();
    }
}

// ---------------- K8: final linear from h2finT ----------------
__global__ __launch_bounds__(256) void k_fin(
    const float* __restrict__ h2finT, const float* __restrict__ W_lin,
    const float* __restrict__ b_lin, float* __restrict__ out, int n_node, int B) {
    __shared__ __align__(16) float hs[128];
    int b = blockIdx.x >> 3;
    int kc = blockIdx.x & 7;
    int tid = threadIdx.x;
    if (tid < 128) hs[tid] = h2finT[tid * 32 + b];
    __syncthreads();
    int outdim = n_node * 2;
    int kk = kc * 256 + tid;
    if (kk < outdim) {
        float acc = b_lin[kk];
        const float4* W4 = (const float4*)(W_lin + (size_t)kk * 128);
        const float4* h4 = (const float4*)hs;
        #pragma unroll 8
        for (int j = 0; j < 32; ++j) {
            float4 w = W4[j], h = h4[j];
            acc += w.x * h.x + w.y * h.y + w.z * h.z + w.w * h.w;
        }
        out[(size_t)b * outdim + kk] = acc;
    }
}

extern "C" void kernel_launch(void* const* d_in, const int* in_sizes, int n_in,
                              void* d_out, int out_size, void* d_ws, size_t ws_size,
                              hipStream_t stream) {
    const float* x     = (const float*)d_in[0];
    const int*   src   = (const int*)d_in[1];
    const int*   dst   = (const int*)d_in[2];
    const float* W_gat = (const float*)d_in[4];
    const float* a_src = (const float*)d_in[5];
    const float* a_dst = (const float*)d_in[6];
    const float* b_gat = (const float*)d_in[7];
    const float* W_ih1 = (const float*)d_in[8];
    const float* W_hh1 = (const float*)d_in[9];
    const float* b_ih1 = (const float*)d_in[10];
    const float* b_hh1 = (const float*)d_in[11];
    const float* W_ih2 = (const float*)d_in[12];
    const float* W_hh2 = (const float*)d_in[13];
    const float* b_ih2 = (const float*)d_in[14];
    const float* b_hh2 = (const float*)d_in[15];
    const float* W_lin = (const float*)d_in[16];
    const float* b_lin = (const float*)d_in[17];

    int N = in_sizes[0] / 32;          // 32000
    int E = in_sizes[1];               // 384000
    int n_node = in_sizes[8] / 128;    // 1000
    int B = N / n_node;                // 32
    int T = 32;

    float* ws = (float*)d_ws;
    float* z      = ws;                                 // N*256
    float* asrc   = z + (size_t)N * 256;                // N*8
    float* adst   = asrc + (size_t)N * 8;               // N*8
    float* gatT   = adst + (size_t)N * 8;               // N*32
    float* P1     = gatT + (size_t)N * 32;              // T*B*128
    float* wc2f   = P1 + (size_t)T * B * 128;           // 8192 uint4 = 32768 f32
    float* wiff   = wc2f + 32768;                       // 2048 uint4 = 8192 f32
    float* w1ff   = wiff + 8192;                        // 512 uint4 = 2048 f32
    float* h2finT = w1ff + 2048;                        // 128*32
    float* wa     = h2finT + 128 * 32;                  // 512
    int* deg     = (int*)(wa + 512);                    // N
    int* cursor  = deg + N;                             // N
    int* rowptr  = cursor + N;                          // N+1
    int* csr_src = rowptr + N + 1;                      // E
    int* blksum  = csr_src + E;                         // 256
    int* blkoff  = blksum + 256;                        // 256
    float* Wt    = (float*)(((uintptr_t)(blkoff + 256) + 255) & ~(uintptr_t)255); // n_node*128

    uint4* wc2p = (uint4*)wc2f;
    uint4* wi2p = (uint4*)wiff;
    uint4* w1p  = (uint4*)w1ff;

    int nb = (N + 255) / 256;   // 125

    k_pack2<<<42, 256, 0, stream>>>(W_hh2, W_ih2, W_hh1, wc2p, wi2p, w1p);
    k_wt<<<128, 256, 0, stream>>>(W_ih1, Wt, n_node);
    k_zero<<<(N + 255) / 256, 256, 0, stream>>>(deg, N);
    k_hist<<<(E + 255) / 256, 256, 0, stream>>>(dst, deg, E);
    k_scan1<<<nb, 256, 0, stream>>>(deg, blksum, N);
    k_scan2<<<1, 256, 0, stream>>>(blksum, blkoff, nb);
    k_scan3<<<nb, 256, 0, stream>>>(deg, blkoff, rowptr, cursor, N, E);
    k_scatter<<<(E + 255) / 256, 256, 0, stream>>>(src, dst, cursor, csr_src, E);
    k_pre<<<1, 256, 0, stream>>>(W_gat, a_src, a_dst, wa);
    k_att<<<N / 32, 256, 0, stream>>>(x, wa, asrc, adst);
    k_gat<<<(N * 64 + 255) / 256, 256, 0, stream>>>(rowptr, csr_src, asrc, adst,
                                                    x, z, N);
    k_zw<<<2000, 256, 0, stream>>>(z, W_gat, b_gat, gatT, N, n_node);
    k_p1<<<B * 16, 256, 0, stream>>>(gatT, Wt, b_ih1, b_hh1, P1, n_node, B);
    k_lstm<<<B, 256, 0, stream>>>(P1, wc2p, wi2p, w1p, b_ih2, b_hh2, h2finT, B, T);
    k_fin<<<B * 8, 256, 0, stream>>>(h2finT, W_lin, b_lin, (float*)d_out, n_node, B);
}